// Round 1
// baseline (5369.595 us; speedup 1.0000x reference)
//
#include <hip/hip_runtime.h>

// ScatterEdges: out[src[e]] += x[e]*sw[e]; out[dst[e]] += x[e]*sw[e]
// E = 3.2M edges, D = 64 f32 features, N = 100K nodes.
// Baseline: 16 threads per edge, each handles one float4 quad of the
// 64-wide feature row. Coalesced float4 reads of x; hardware f32 atomics
// into out (25.6 MB output -> L2-resident accumulation).

#define D_FEAT 64

__global__ __launch_bounds__(256) void scatter_edges_kernel(
    const float4* __restrict__ x,      // [E, 16] as float4
    const float*  __restrict__ sw,     // [E]
    const int*    __restrict__ src,    // [E]
    const int*    __restrict__ dst,    // [E]
    float*        __restrict__ out,    // [N, 64]
    int n_edges)
{
    long long tid = (long long)blockIdx.x * blockDim.x + threadIdx.x;
    long long total = (long long)n_edges * 16;  // 16 float4 quads per edge
    if (tid >= total) return;

    int e = (int)(tid >> 4);
    int q = (int)(tid & 15);

    float s = sw[e];
    float4 v = x[(long long)e * 16 + q];
    v.x *= s; v.y *= s; v.z *= s; v.w *= s;

    int a = src[e];
    int b = dst[e];

    float* oa = out + (long long)a * D_FEAT + q * 4;
    float* ob = out + (long long)b * D_FEAT + q * 4;

    unsafeAtomicAdd(oa + 0, v.x);
    unsafeAtomicAdd(oa + 1, v.y);
    unsafeAtomicAdd(oa + 2, v.z);
    unsafeAtomicAdd(oa + 3, v.w);

    unsafeAtomicAdd(ob + 0, v.x);
    unsafeAtomicAdd(ob + 1, v.y);
    unsafeAtomicAdd(ob + 2, v.z);
    unsafeAtomicAdd(ob + 3, v.w);
}

extern "C" void kernel_launch(void* const* d_in, const int* in_sizes, int n_in,
                              void* d_out, int out_size, void* d_ws, size_t ws_size,
                              hipStream_t stream) {
    const float4* x  = (const float4*)d_in[0];   // [E, 64] f32
    const float*  sw = (const float*)d_in[1];    // [E]
    const int*    src = (const int*)d_in[2];     // [E]
    const int*    dst = (const int*)d_in[3];     // [E]
    // d_in[4] = species, only used for node count
    float* out = (float*)d_out;

    int n_edges = in_sizes[1];                   // E from switch array

    // Output is accumulated via atomics; d_out is poisoned -> zero it first.
    hipMemsetAsync(d_out, 0, (size_t)out_size * sizeof(float), stream);

    long long total = (long long)n_edges * 16;
    int block = 256;
    long long grid = (total + block - 1) / block;

    scatter_edges_kernel<<<(int)grid, block, 0, stream>>>(
        x, sw, src, dst, out, n_edges);
}

// Round 2
// 1191.016 us; speedup vs baseline: 4.5084x; 4.5084x over previous
//
#include <hip/hip_runtime.h>

// ScatterEdges via on-device CSR build + gather.
// out[n] = sum over edges e with src[e]==n or dst[e]==n of x[e]*sw[e].
//
// Phase 1: degree histogram (int atomics, 400KB counters)
// Phase 2: exclusive scan of counts (3 small kernels)
// Phase 3: scatter edge ids into per-node lists (int atomics)
// Phase 4: gather -- one wave per node, lane = feature column, coalesced
//          256B row reads of x, no f32 atomics at all.

#define D_FEAT 64
#define SCAN_BLK 1024

// ---------------- fallback (round-1 atomic version) ----------------
__global__ __launch_bounds__(256) void scatter_edges_atomic_kernel(
    const float4* __restrict__ x, const float* __restrict__ sw,
    const int* __restrict__ src, const int* __restrict__ dst,
    float* __restrict__ out, int n_edges)
{
    long long tid = (long long)blockIdx.x * blockDim.x + threadIdx.x;
    long long total = (long long)n_edges * 16;
    if (tid >= total) return;
    int e = (int)(tid >> 4);
    int q = (int)(tid & 15);
    float s = sw[e];
    float4 v = x[(long long)e * 16 + q];
    v.x *= s; v.y *= s; v.z *= s; v.w *= s;
    float* oa = out + (long long)src[e] * D_FEAT + q * 4;
    float* ob = out + (long long)dst[e] * D_FEAT + q * 4;
    unsafeAtomicAdd(oa + 0, v.x); unsafeAtomicAdd(oa + 1, v.y);
    unsafeAtomicAdd(oa + 2, v.z); unsafeAtomicAdd(oa + 3, v.w);
    unsafeAtomicAdd(ob + 0, v.x); unsafeAtomicAdd(ob + 1, v.y);
    unsafeAtomicAdd(ob + 2, v.z); unsafeAtomicAdd(ob + 3, v.w);
}

// ---------------- phase 1: degree histogram ----------------
__global__ __launch_bounds__(256) void hist_kernel(
    const int* __restrict__ src, const int* __restrict__ dst,
    int* __restrict__ counts, int n_edges)
{
    int e = blockIdx.x * blockDim.x + threadIdx.x;
    if (e >= n_edges) return;
    atomicAdd(&counts[src[e]], 1);
    atomicAdd(&counts[dst[e]], 1);
}

// ---------------- phase 2: hierarchical exclusive scan ----------------
// scan1: per-block (1024 elems) exclusive scan -> offs, block total -> bsum
__global__ __launch_bounds__(SCAN_BLK) void scan1_kernel(
    const int* __restrict__ counts, int* __restrict__ offs,
    int* __restrict__ bsum, int n)
{
    __shared__ int lds[SCAN_BLK];
    int t = threadIdx.x;
    int i = blockIdx.x * SCAN_BLK + t;
    int v = (i < n) ? counts[i] : 0;
    int acc = v;
    lds[t] = acc;
    __syncthreads();
    for (int d = 1; d < SCAN_BLK; d <<= 1) {
        int add = (t >= d) ? lds[t - d] : 0;
        __syncthreads();
        acc += add;
        lds[t] = acc;
        __syncthreads();
    }
    if (i < n) offs[i] = acc - v;          // exclusive within block
    if (t == SCAN_BLK - 1) bsum[blockIdx.x] = acc;  // block total
}

// scan2: single block exclusive scan of block sums -> bbase
__global__ __launch_bounds__(SCAN_BLK) void scan2_kernel(
    const int* __restrict__ bsum, int* __restrict__ bbase, int nb)
{
    __shared__ int lds[SCAN_BLK];
    int t = threadIdx.x;
    int v = (t < nb) ? bsum[t] : 0;
    int acc = v;
    lds[t] = acc;
    __syncthreads();
    for (int d = 1; d < SCAN_BLK; d <<= 1) {
        int add = (t >= d) ? lds[t - d] : 0;
        __syncthreads();
        acc += add;
        lds[t] = acc;
        __syncthreads();
    }
    if (t < nb) bbase[t] = acc - v;        // exclusive
}

// scan3: add block bases; also init the scatter cursor
__global__ __launch_bounds__(SCAN_BLK) void scan3_kernel(
    int* __restrict__ offs, const int* __restrict__ bbase,
    int* __restrict__ cursor, int n)
{
    int i = blockIdx.x * SCAN_BLK + threadIdx.x;
    if (i >= n) return;
    int o = offs[i] + bbase[blockIdx.x];
    offs[i] = o;
    cursor[i] = o;
}

// ---------------- phase 3: scatter edge ids ----------------
__global__ __launch_bounds__(256) void scatter_ids_kernel(
    const int* __restrict__ src, const int* __restrict__ dst,
    int* __restrict__ cursor, int* __restrict__ list, int n_edges)
{
    int e = blockIdx.x * blockDim.x + threadIdx.x;
    if (e >= n_edges) return;
    int p = atomicAdd(&cursor[src[e]], 1);
    list[p] = e;
    int q = atomicAdd(&cursor[dst[e]], 1);
    list[q] = e;
}

// ---------------- phase 4: gather ----------------
// One 64-lane wave per node; lane = feature column. Coalesced 256B row
// reads of x; 4 edges in flight per wave for memory-level parallelism.
__global__ __launch_bounds__(256) void gather_kernel(
    const float* __restrict__ x, const float* __restrict__ sw,
    const int* __restrict__ offs, const int* __restrict__ counts,
    const int* __restrict__ list, float* __restrict__ out, int n_nodes)
{
    int wave = blockIdx.x * (blockDim.x >> 6) + (threadIdx.x >> 6);
    int lane = threadIdx.x & 63;
    if (wave >= n_nodes) return;
    int n = wave;
    int start = offs[n];
    int cnt = counts[n];

    float acc = 0.0f;
    int i = 0;
    for (; i + 4 <= cnt; i += 4) {
        int e0 = list[start + i + 0];
        int e1 = list[start + i + 1];
        int e2 = list[start + i + 2];
        int e3 = list[start + i + 3];
        float v0 = x[(long long)e0 * D_FEAT + lane];
        float v1 = x[(long long)e1 * D_FEAT + lane];
        float v2 = x[(long long)e2 * D_FEAT + lane];
        float v3 = x[(long long)e3 * D_FEAT + lane];
        float s0 = sw[e0], s1 = sw[e1], s2 = sw[e2], s3 = sw[e3];
        acc += v0 * s0;
        acc += v1 * s1;
        acc += v2 * s2;
        acc += v3 * s3;
    }
    for (; i < cnt; ++i) {
        int e = list[start + i];
        acc += x[(long long)e * D_FEAT + lane] * sw[e];
    }
    out[(long long)n * D_FEAT + lane] = acc;
}

extern "C" void kernel_launch(void* const* d_in, const int* in_sizes, int n_in,
                              void* d_out, int out_size, void* d_ws, size_t ws_size,
                              hipStream_t stream) {
    const float* x   = (const float*)d_in[0];   // [E, 64]
    const float* sw  = (const float*)d_in[1];   // [E]
    const int*   src = (const int*)d_in[2];     // [E]
    const int*   dst = (const int*)d_in[3];     // [E]
    float* out = (float*)d_out;

    int n_edges = in_sizes[1];
    int n_nodes = in_sizes[4];                  // species length

    // Workspace layout (256B-aligned regions)
    size_t nb = (((size_t)n_nodes * 4) + 255) & ~(size_t)255;
    char* wsb = (char*)d_ws;
    int* counts = (int*)(wsb + 0);
    int* offs   = (int*)(wsb + nb);
    int* cursor = (int*)(wsb + 2 * nb);
    int* bsum   = (int*)(wsb + 3 * nb);
    int* bbase  = (int*)(wsb + 3 * nb + 4096);
    int* list   = (int*)(wsb + 3 * nb + 8192);
    size_t needed = 3 * nb + 8192 + (size_t)n_edges * 2 * 4;

    if (ws_size < needed) {
        // Fallback: direct atomic scatter (round-1 kernel)
        hipMemsetAsync(d_out, 0, (size_t)out_size * sizeof(float), stream);
        long long total = (long long)n_edges * 16;
        int block = 256;
        long long grid = (total + block - 1) / block;
        scatter_edges_atomic_kernel<<<(int)grid, block, 0, stream>>>(
            (const float4*)x, sw, src, dst, out, n_edges);
        return;
    }

    int nblk_scan = (n_nodes + SCAN_BLK - 1) / SCAN_BLK;  // 98 for N=100K

    // Phase 0: zero counters (only region that needs zeroing)
    hipMemsetAsync(counts, 0, (size_t)n_nodes * 4, stream);

    // Phase 1: histogram
    int eblk = (n_edges + 255) / 256;
    hist_kernel<<<eblk, 256, 0, stream>>>(src, dst, counts, n_edges);

    // Phase 2: scan
    scan1_kernel<<<nblk_scan, SCAN_BLK, 0, stream>>>(counts, offs, bsum, n_nodes);
    scan2_kernel<<<1, SCAN_BLK, 0, stream>>>(bsum, bbase, nblk_scan);
    scan3_kernel<<<nblk_scan, SCAN_BLK, 0, stream>>>(offs, bbase, cursor, n_nodes);

    // Phase 3: scatter edge ids
    scatter_ids_kernel<<<eblk, 256, 0, stream>>>(src, dst, cursor, list, n_edges);

    // Phase 4: gather (writes every output element -> no out memset needed)
    int waves_per_blk = 4;  // 256 threads
    int gblk = (n_nodes + waves_per_blk - 1) / waves_per_blk;
    gather_kernel<<<gblk, 256, 0, stream>>>(x, sw, offs, counts, list, out, n_nodes);
}

// Round 3
// 1150.722 us; speedup vs baseline: 4.6663x; 1.0350x over previous
//
#include <hip/hip_runtime.h>

// ScatterEdges via on-device CSR build + gather.
// out[n] = sum over edges e with src[e]==n or dst[e]==n of x[e]*sw[e].
//
// Round-3 change: batch the latency-bound index kernels. Each thread in
// hist/scatter_ids handles 4-8 edges via int4 loads, issuing 8-16
// INDEPENDENT atomic chains -> latency amortized (round-2 scatter_ids ran
// at 21 G ops/s vs the 76 G ops/s the atomic engine sustained in round 1;
// it was dependency-latency-bound, not throughput-bound).

#define D_FEAT 64
#define SCAN_BLK 1024

// ---------------- fallback (round-1 atomic version) ----------------
__global__ __launch_bounds__(256) void scatter_edges_atomic_kernel(
    const float4* __restrict__ x, const float* __restrict__ sw,
    const int* __restrict__ src, const int* __restrict__ dst,
    float* __restrict__ out, int n_edges)
{
    long long tid = (long long)blockIdx.x * blockDim.x + threadIdx.x;
    long long total = (long long)n_edges * 16;
    if (tid >= total) return;
    int e = (int)(tid >> 4);
    int q = (int)(tid & 15);
    float s = sw[e];
    float4 v = x[(long long)e * 16 + q];
    v.x *= s; v.y *= s; v.z *= s; v.w *= s;
    float* oa = out + (long long)src[e] * D_FEAT + q * 4;
    float* ob = out + (long long)dst[e] * D_FEAT + q * 4;
    unsafeAtomicAdd(oa + 0, v.x); unsafeAtomicAdd(oa + 1, v.y);
    unsafeAtomicAdd(oa + 2, v.z); unsafeAtomicAdd(oa + 3, v.w);
    unsafeAtomicAdd(ob + 0, v.x); unsafeAtomicAdd(ob + 1, v.y);
    unsafeAtomicAdd(ob + 2, v.z); unsafeAtomicAdd(ob + 3, v.w);
}

// ---------------- phase 1: degree histogram (8 edges/thread) ----------------
__global__ __launch_bounds__(256) void hist_kernel(
    const int* __restrict__ src, const int* __restrict__ dst,
    int* __restrict__ counts, int n_edges)
{
    int t = blockIdx.x * blockDim.x + threadIdx.x;
    int e0 = t * 8;
    if (e0 >= n_edges) return;
    if (e0 + 8 <= n_edges) {
        const int4* s4 = (const int4*)(src + e0);
        const int4* d4 = (const int4*)(dst + e0);
        int4 sa = s4[0], sb = s4[1];
        int4 da = d4[0], db = d4[1];
        atomicAdd(&counts[sa.x], 1); atomicAdd(&counts[sa.y], 1);
        atomicAdd(&counts[sa.z], 1); atomicAdd(&counts[sa.w], 1);
        atomicAdd(&counts[sb.x], 1); atomicAdd(&counts[sb.y], 1);
        atomicAdd(&counts[sb.z], 1); atomicAdd(&counts[sb.w], 1);
        atomicAdd(&counts[da.x], 1); atomicAdd(&counts[da.y], 1);
        atomicAdd(&counts[da.z], 1); atomicAdd(&counts[da.w], 1);
        atomicAdd(&counts[db.x], 1); atomicAdd(&counts[db.y], 1);
        atomicAdd(&counts[db.z], 1); atomicAdd(&counts[db.w], 1);
    } else {
        for (int e = e0; e < n_edges; ++e) {
            atomicAdd(&counts[src[e]], 1);
            atomicAdd(&counts[dst[e]], 1);
        }
    }
}

// ---------------- phase 2: hierarchical exclusive scan ----------------
__global__ __launch_bounds__(SCAN_BLK) void scan1_kernel(
    const int* __restrict__ counts, int* __restrict__ offs,
    int* __restrict__ bsum, int n)
{
    __shared__ int lds[SCAN_BLK];
    int t = threadIdx.x;
    int i = blockIdx.x * SCAN_BLK + t;
    int v = (i < n) ? counts[i] : 0;
    int acc = v;
    lds[t] = acc;
    __syncthreads();
    for (int d = 1; d < SCAN_BLK; d <<= 1) {
        int add = (t >= d) ? lds[t - d] : 0;
        __syncthreads();
        acc += add;
        lds[t] = acc;
        __syncthreads();
    }
    if (i < n) offs[i] = acc - v;
    if (t == SCAN_BLK - 1) bsum[blockIdx.x] = acc;
}

__global__ __launch_bounds__(SCAN_BLK) void scan2_kernel(
    const int* __restrict__ bsum, int* __restrict__ bbase, int nb)
{
    __shared__ int lds[SCAN_BLK];
    int t = threadIdx.x;
    int v = (t < nb) ? bsum[t] : 0;
    int acc = v;
    lds[t] = acc;
    __syncthreads();
    for (int d = 1; d < SCAN_BLK; d <<= 1) {
        int add = (t >= d) ? lds[t - d] : 0;
        __syncthreads();
        acc += add;
        lds[t] = acc;
        __syncthreads();
    }
    if (t < nb) bbase[t] = acc - v;
}

__global__ __launch_bounds__(SCAN_BLK) void scan3_kernel(
    int* __restrict__ offs, const int* __restrict__ bbase,
    int* __restrict__ cursor, int n)
{
    int i = blockIdx.x * SCAN_BLK + threadIdx.x;
    if (i >= n) return;
    int o = offs[i] + bbase[blockIdx.x];
    offs[i] = o;
    cursor[i] = o;
}

// ---------------- phase 3: scatter edge ids (4 edges/thread) ----------------
__global__ __launch_bounds__(256) void scatter_ids_kernel(
    const int* __restrict__ src, const int* __restrict__ dst,
    int* __restrict__ cursor, int* __restrict__ list, int n_edges)
{
    int t = blockIdx.x * blockDim.x + threadIdx.x;
    int e0 = t * 4;
    if (e0 >= n_edges) return;
    if (e0 + 4 <= n_edges) {
        int4 s = *(const int4*)(src + e0);
        int4 d = *(const int4*)(dst + e0);
        // 8 independent atomic chains in flight
        int p0 = atomicAdd(&cursor[s.x], 1);
        int p1 = atomicAdd(&cursor[s.y], 1);
        int p2 = atomicAdd(&cursor[s.z], 1);
        int p3 = atomicAdd(&cursor[s.w], 1);
        int q0 = atomicAdd(&cursor[d.x], 1);
        int q1 = atomicAdd(&cursor[d.y], 1);
        int q2 = atomicAdd(&cursor[d.z], 1);
        int q3 = atomicAdd(&cursor[d.w], 1);
        list[p0] = e0 + 0; list[p1] = e0 + 1;
        list[p2] = e0 + 2; list[p3] = e0 + 3;
        list[q0] = e0 + 0; list[q1] = e0 + 1;
        list[q2] = e0 + 2; list[q3] = e0 + 3;
    } else {
        for (int e = e0; e < n_edges; ++e) {
            int p = atomicAdd(&cursor[src[e]], 1);
            list[p] = e;
            int q = atomicAdd(&cursor[dst[e]], 1);
            list[q] = e;
        }
    }
}

// ---------------- phase 4: gather ----------------
// One 64-lane wave per node; lane = feature column. Coalesced 256B row
// reads of x; 8 edges in flight per wave for memory-level parallelism.
__global__ __launch_bounds__(256) void gather_kernel(
    const float* __restrict__ x, const float* __restrict__ sw,
    const int* __restrict__ offs, const int* __restrict__ counts,
    const int* __restrict__ list, float* __restrict__ out, int n_nodes)
{
    int wave = blockIdx.x * (blockDim.x >> 6) + (threadIdx.x >> 6);
    int lane = threadIdx.x & 63;
    if (wave >= n_nodes) return;
    int n = wave;
    int start = offs[n];
    int cnt = counts[n];

    float acc = 0.0f;
    int i = 0;
    for (; i + 8 <= cnt; i += 8) {
        int e0 = list[start + i + 0];
        int e1 = list[start + i + 1];
        int e2 = list[start + i + 2];
        int e3 = list[start + i + 3];
        int e4 = list[start + i + 4];
        int e5 = list[start + i + 5];
        int e6 = list[start + i + 6];
        int e7 = list[start + i + 7];
        float v0 = x[(long long)e0 * D_FEAT + lane];
        float v1 = x[(long long)e1 * D_FEAT + lane];
        float v2 = x[(long long)e2 * D_FEAT + lane];
        float v3 = x[(long long)e3 * D_FEAT + lane];
        float v4 = x[(long long)e4 * D_FEAT + lane];
        float v5 = x[(long long)e5 * D_FEAT + lane];
        float v6 = x[(long long)e6 * D_FEAT + lane];
        float v7 = x[(long long)e7 * D_FEAT + lane];
        float s0 = sw[e0], s1 = sw[e1], s2 = sw[e2], s3 = sw[e3];
        float s4 = sw[e4], s5 = sw[e5], s6 = sw[e6], s7 = sw[e7];
        acc += v0 * s0; acc += v1 * s1; acc += v2 * s2; acc += v3 * s3;
        acc += v4 * s4; acc += v5 * s5; acc += v6 * s6; acc += v7 * s7;
    }
    for (; i < cnt; ++i) {
        int e = list[start + i];
        acc += x[(long long)e * D_FEAT + lane] * sw[e];
    }
    out[(long long)n * D_FEAT + lane] = acc;
}

extern "C" void kernel_launch(void* const* d_in, const int* in_sizes, int n_in,
                              void* d_out, int out_size, void* d_ws, size_t ws_size,
                              hipStream_t stream) {
    const float* x   = (const float*)d_in[0];   // [E, 64]
    const float* sw  = (const float*)d_in[1];   // [E]
    const int*   src = (const int*)d_in[2];     // [E]
    const int*   dst = (const int*)d_in[3];     // [E]
    float* out = (float*)d_out;

    int n_edges = in_sizes[1];
    int n_nodes = in_sizes[4];                  // species length

    size_t nb = (((size_t)n_nodes * 4) + 255) & ~(size_t)255;
    char* wsb = (char*)d_ws;
    int* counts = (int*)(wsb + 0);
    int* offs   = (int*)(wsb + nb);
    int* cursor = (int*)(wsb + 2 * nb);
    int* bsum   = (int*)(wsb + 3 * nb);
    int* bbase  = (int*)(wsb + 3 * nb + 4096);
    int* list   = (int*)(wsb + 3 * nb + 8192);
    size_t needed = 3 * nb + 8192 + (size_t)n_edges * 2 * 4;

    if (ws_size < needed) {
        hipMemsetAsync(d_out, 0, (size_t)out_size * sizeof(float), stream);
        long long total = (long long)n_edges * 16;
        int block = 256;
        long long grid = (total + block - 1) / block;
        scatter_edges_atomic_kernel<<<(int)grid, block, 0, stream>>>(
            (const float4*)x, sw, src, dst, out, n_edges);
        return;
    }

    int nblk_scan = (n_nodes + SCAN_BLK - 1) / SCAN_BLK;

    hipMemsetAsync(counts, 0, (size_t)n_nodes * 4, stream);

    // Phase 1: histogram, 8 edges per thread
    int t1 = (n_edges + 7) / 8;
    hist_kernel<<<(t1 + 255) / 256, 256, 0, stream>>>(src, dst, counts, n_edges);

    // Phase 2: scan
    scan1_kernel<<<nblk_scan, SCAN_BLK, 0, stream>>>(counts, offs, bsum, n_nodes);
    scan2_kernel<<<1, SCAN_BLK, 0, stream>>>(bsum, bbase, nblk_scan);
    scan3_kernel<<<nblk_scan, SCAN_BLK, 0, stream>>>(offs, bbase, cursor, n_nodes);

    // Phase 3: scatter edge ids, 4 edges per thread
    int t3 = (n_edges + 3) / 4;
    scatter_ids_kernel<<<(t3 + 255) / 256, 256, 0, stream>>>(src, dst, cursor, list, n_edges);

    // Phase 4: gather (writes every output element -> no out memset needed)
    int waves_per_blk = 4;
    int gblk = (n_nodes + waves_per_blk - 1) / waves_per_blk;
    gather_kernel<<<gblk, 256, 0, stream>>>(x, sw, offs, counts, list, out, n_nodes);
}

// Round 4
// 1149.437 us; speedup vs baseline: 4.6715x; 1.0011x over previous
//
#include <hip/hip_runtime.h>

// ScatterEdges via on-device CSR build + gather.
// out[n] = sum over edges e with src[e]==n or dst[e]==n of x[e]*sw[e].
//
// Round-4 change: pad per-node atomic counters (counts, cursor) to one per
// 64B cache line (stride 16 ints). Round-3 showed scatter_ids pinned at
// ~590us regardless of per-thread batching -> same-cache-line atomic RMW
// serialization at the coherence point (16 counters/line x 64 ops each =
// 1024 serialized RMWs/line). Padding spreads this over 16x more lines.
// Also: 8 edges/thread in scatter_ids (MLP useful once serialization gone),
// nontemporal loads for the streamed x rows in gather.

#define D_FEAT 64
#define SCAN_BLK 1024

// ---------------- fallback (round-1 atomic version) ----------------
__global__ __launch_bounds__(256) void scatter_edges_atomic_kernel(
    const float4* __restrict__ x, const float* __restrict__ sw,
    const int* __restrict__ src, const int* __restrict__ dst,
    float* __restrict__ out, int n_edges)
{
    long long tid = (long long)blockIdx.x * blockDim.x + threadIdx.x;
    long long total = (long long)n_edges * 16;
    if (tid >= total) return;
    int e = (int)(tid >> 4);
    int q = (int)(tid & 15);
    float s = sw[e];
    float4 v = x[(long long)e * 16 + q];
    v.x *= s; v.y *= s; v.z *= s; v.w *= s;
    float* oa = out + (long long)src[e] * D_FEAT + q * 4;
    float* ob = out + (long long)dst[e] * D_FEAT + q * 4;
    unsafeAtomicAdd(oa + 0, v.x); unsafeAtomicAdd(oa + 1, v.y);
    unsafeAtomicAdd(oa + 2, v.z); unsafeAtomicAdd(oa + 3, v.w);
    unsafeAtomicAdd(ob + 0, v.x); unsafeAtomicAdd(ob + 1, v.y);
    unsafeAtomicAdd(ob + 2, v.z); unsafeAtomicAdd(ob + 3, v.w);
}

// ---------------- phase 1: degree histogram (8 edges/thread) ----------------
// counts are strided: counts[n * cstride]
__global__ __launch_bounds__(256) void hist_kernel(
    const int* __restrict__ src, const int* __restrict__ dst,
    int* __restrict__ counts, int n_edges, int cstride)
{
    int t = blockIdx.x * blockDim.x + threadIdx.x;
    int e0 = t * 8;
    if (e0 >= n_edges) return;
    if (e0 + 8 <= n_edges) {
        const int4* s4 = (const int4*)(src + e0);
        const int4* d4 = (const int4*)(dst + e0);
        int4 sa = s4[0], sb = s4[1];
        int4 da = d4[0], db = d4[1];
        atomicAdd(&counts[sa.x * cstride], 1); atomicAdd(&counts[sa.y * cstride], 1);
        atomicAdd(&counts[sa.z * cstride], 1); atomicAdd(&counts[sa.w * cstride], 1);
        atomicAdd(&counts[sb.x * cstride], 1); atomicAdd(&counts[sb.y * cstride], 1);
        atomicAdd(&counts[sb.z * cstride], 1); atomicAdd(&counts[sb.w * cstride], 1);
        atomicAdd(&counts[da.x * cstride], 1); atomicAdd(&counts[da.y * cstride], 1);
        atomicAdd(&counts[da.z * cstride], 1); atomicAdd(&counts[da.w * cstride], 1);
        atomicAdd(&counts[db.x * cstride], 1); atomicAdd(&counts[db.y * cstride], 1);
        atomicAdd(&counts[db.z * cstride], 1); atomicAdd(&counts[db.w * cstride], 1);
    } else {
        for (int e = e0; e < n_edges; ++e) {
            atomicAdd(&counts[src[e] * cstride], 1);
            atomicAdd(&counts[dst[e] * cstride], 1);
        }
    }
}

// ---------------- phase 2: hierarchical exclusive scan ----------------
// reads strided counts, writes DENSE offs
__global__ __launch_bounds__(SCAN_BLK) void scan1_kernel(
    const int* __restrict__ counts, int* __restrict__ offs,
    int* __restrict__ bsum, int n, int cstride)
{
    __shared__ int lds[SCAN_BLK];
    int t = threadIdx.x;
    int i = blockIdx.x * SCAN_BLK + t;
    int v = (i < n) ? counts[i * cstride] : 0;
    int acc = v;
    lds[t] = acc;
    __syncthreads();
    for (int d = 1; d < SCAN_BLK; d <<= 1) {
        int add = (t >= d) ? lds[t - d] : 0;
        __syncthreads();
        acc += add;
        lds[t] = acc;
        __syncthreads();
    }
    if (i < n) offs[i] = acc - v;
    if (t == SCAN_BLK - 1) bsum[blockIdx.x] = acc;
}

__global__ __launch_bounds__(SCAN_BLK) void scan2_kernel(
    const int* __restrict__ bsum, int* __restrict__ bbase, int nb)
{
    __shared__ int lds[SCAN_BLK];
    int t = threadIdx.x;
    int v = (t < nb) ? bsum[t] : 0;
    int acc = v;
    lds[t] = acc;
    __syncthreads();
    for (int d = 1; d < SCAN_BLK; d <<= 1) {
        int add = (t >= d) ? lds[t - d] : 0;
        __syncthreads();
        acc += add;
        lds[t] = acc;
        __syncthreads();
    }
    if (t < nb) bbase[t] = acc - v;
}

// offs becomes dense exclusive scan; cursor (strided) initialized to offs
__global__ __launch_bounds__(SCAN_BLK) void scan3_kernel(
    int* __restrict__ offs, const int* __restrict__ bbase,
    int* __restrict__ cursor, int n, int cstride)
{
    int i = blockIdx.x * SCAN_BLK + threadIdx.x;
    if (i >= n) return;
    int o = offs[i] + bbase[blockIdx.x];
    offs[i] = o;
    cursor[i * cstride] = o;
}

// ---------------- phase 3: scatter edge ids (8 edges/thread) ----------------
__global__ __launch_bounds__(256) void scatter_ids_kernel(
    const int* __restrict__ src, const int* __restrict__ dst,
    int* __restrict__ cursor, int* __restrict__ list, int n_edges, int cstride)
{
    int t = blockIdx.x * blockDim.x + threadIdx.x;
    int e0 = t * 8;
    if (e0 >= n_edges) return;
    if (e0 + 8 <= n_edges) {
        const int4* s4 = (const int4*)(src + e0);
        const int4* d4 = (const int4*)(dst + e0);
        int4 sa = s4[0], sb = s4[1];
        int4 da = d4[0], db = d4[1];
        // 16 independent returning atomics in flight
        int p0 = atomicAdd(&cursor[sa.x * cstride], 1);
        int p1 = atomicAdd(&cursor[sa.y * cstride], 1);
        int p2 = atomicAdd(&cursor[sa.z * cstride], 1);
        int p3 = atomicAdd(&cursor[sa.w * cstride], 1);
        int p4 = atomicAdd(&cursor[sb.x * cstride], 1);
        int p5 = atomicAdd(&cursor[sb.y * cstride], 1);
        int p6 = atomicAdd(&cursor[sb.z * cstride], 1);
        int p7 = atomicAdd(&cursor[sb.w * cstride], 1);
        int q0 = atomicAdd(&cursor[da.x * cstride], 1);
        int q1 = atomicAdd(&cursor[da.y * cstride], 1);
        int q2 = atomicAdd(&cursor[da.z * cstride], 1);
        int q3 = atomicAdd(&cursor[da.w * cstride], 1);
        int q4 = atomicAdd(&cursor[db.x * cstride], 1);
        int q5 = atomicAdd(&cursor[db.y * cstride], 1);
        int q6 = atomicAdd(&cursor[db.z * cstride], 1);
        int q7 = atomicAdd(&cursor[db.w * cstride], 1);
        list[p0] = e0 + 0; list[p1] = e0 + 1;
        list[p2] = e0 + 2; list[p3] = e0 + 3;
        list[p4] = e0 + 4; list[p5] = e0 + 5;
        list[p6] = e0 + 6; list[p7] = e0 + 7;
        list[q0] = e0 + 0; list[q1] = e0 + 1;
        list[q2] = e0 + 2; list[q3] = e0 + 3;
        list[q4] = e0 + 4; list[q5] = e0 + 5;
        list[q6] = e0 + 6; list[q7] = e0 + 7;
    } else {
        for (int e = e0; e < n_edges; ++e) {
            int p = atomicAdd(&cursor[src[e] * cstride], 1);
            list[p] = e;
            int q = atomicAdd(&cursor[dst[e] * cstride], 1);
            list[q] = e;
        }
    }
}

// ---------------- phase 4: gather ----------------
// One 64-lane wave per node; lane = feature column. Coalesced 256B row
// reads of x (nontemporal: streamed, no reuse), 8 edges in flight.
__global__ __launch_bounds__(256) void gather_kernel(
    const float* __restrict__ x, const float* __restrict__ sw,
    const int* __restrict__ offs, const int* __restrict__ counts,
    const int* __restrict__ list, float* __restrict__ out,
    int n_nodes, int cstride)
{
    int wave = blockIdx.x * (blockDim.x >> 6) + (threadIdx.x >> 6);
    int lane = threadIdx.x & 63;
    if (wave >= n_nodes) return;
    int n = wave;
    int start = offs[n];
    int cnt = counts[n * cstride];

    float acc = 0.0f;
    int i = 0;
    for (; i + 8 <= cnt; i += 8) {
        int e0 = list[start + i + 0];
        int e1 = list[start + i + 1];
        int e2 = list[start + i + 2];
        int e3 = list[start + i + 3];
        int e4 = list[start + i + 4];
        int e5 = list[start + i + 5];
        int e6 = list[start + i + 6];
        int e7 = list[start + i + 7];
        float v0 = __builtin_nontemporal_load(x + (long long)e0 * D_FEAT + lane);
        float v1 = __builtin_nontemporal_load(x + (long long)e1 * D_FEAT + lane);
        float v2 = __builtin_nontemporal_load(x + (long long)e2 * D_FEAT + lane);
        float v3 = __builtin_nontemporal_load(x + (long long)e3 * D_FEAT + lane);
        float v4 = __builtin_nontemporal_load(x + (long long)e4 * D_FEAT + lane);
        float v5 = __builtin_nontemporal_load(x + (long long)e5 * D_FEAT + lane);
        float v6 = __builtin_nontemporal_load(x + (long long)e6 * D_FEAT + lane);
        float v7 = __builtin_nontemporal_load(x + (long long)e7 * D_FEAT + lane);
        float s0 = sw[e0], s1 = sw[e1], s2 = sw[e2], s3 = sw[e3];
        float s4 = sw[e4], s5 = sw[e5], s6 = sw[e6], s7 = sw[e7];
        acc += v0 * s0; acc += v1 * s1; acc += v2 * s2; acc += v3 * s3;
        acc += v4 * s4; acc += v5 * s5; acc += v6 * s6; acc += v7 * s7;
    }
    for (; i < cnt; ++i) {
        int e = list[start + i];
        acc += __builtin_nontemporal_load(x + (long long)e * D_FEAT + lane) * sw[e];
    }
    out[(long long)n * D_FEAT + lane] = acc;
}

extern "C" void kernel_launch(void* const* d_in, const int* in_sizes, int n_in,
                              void* d_out, int out_size, void* d_ws, size_t ws_size,
                              hipStream_t stream) {
    const float* x   = (const float*)d_in[0];   // [E, 64]
    const float* sw  = (const float*)d_in[1];   // [E]
    const int*   src = (const int*)d_in[2];     // [E]
    const int*   dst = (const int*)d_in[3];     // [E]
    float* out = (float*)d_out;

    int n_edges = in_sizes[1];
    int n_nodes = in_sizes[4];                  // species length

    // Try padded layout first (stride 16 ints = one counter per 64B line),
    // fall back to dense stride if workspace is tight.
    for (int cstride = 16; cstride >= 1; cstride >>= 4) {
        size_t nbp = (((size_t)n_nodes * cstride * 4) + 255) & ~(size_t)255; // counts/cursor
        size_t nbd = (((size_t)n_nodes * 4) + 255) & ~(size_t)255;           // dense offs
        char* wsb = (char*)d_ws;
        int* counts = (int*)(wsb + 0);
        int* cursor = (int*)(wsb + nbp);
        int* offs   = (int*)(wsb + 2 * nbp);
        int* bsum   = (int*)(wsb + 2 * nbp + nbd);
        int* bbase  = (int*)(wsb + 2 * nbp + nbd + 4096);
        int* list   = (int*)(wsb + 2 * nbp + nbd + 8192);
        size_t needed = 2 * nbp + nbd + 8192 + (size_t)n_edges * 2 * 4;
        if (ws_size < needed) continue;

        int nblk_scan = (n_nodes + SCAN_BLK - 1) / SCAN_BLK;

        // zero strided counts region
        hipMemsetAsync(counts, 0, (size_t)n_nodes * cstride * 4, stream);

        int t1 = (n_edges + 7) / 8;
        hist_kernel<<<(t1 + 255) / 256, 256, 0, stream>>>(
            src, dst, counts, n_edges, cstride);

        scan1_kernel<<<nblk_scan, SCAN_BLK, 0, stream>>>(
            counts, offs, bsum, n_nodes, cstride);
        scan2_kernel<<<1, SCAN_BLK, 0, stream>>>(bsum, bbase, nblk_scan);
        scan3_kernel<<<nblk_scan, SCAN_BLK, 0, stream>>>(
            offs, bbase, cursor, n_nodes, cstride);

        int t3 = (n_edges + 7) / 8;
        scatter_ids_kernel<<<(t3 + 255) / 256, 256, 0, stream>>>(
            src, dst, cursor, list, n_edges, cstride);

        int waves_per_blk = 4;
        int gblk = (n_nodes + waves_per_blk - 1) / waves_per_blk;
        gather_kernel<<<gblk, 256, 0, stream>>>(
            x, sw, offs, counts, list, out, n_nodes, cstride);
        return;
    }

    // Last resort: direct atomic scatter
    hipMemsetAsync(d_out, 0, (size_t)out_size * sizeof(float), stream);
    long long total = (long long)n_edges * 16;
    int block = 256;
    long long grid = (total + block - 1) / block;
    scatter_edges_atomic_kernel<<<(int)grid, block, 0, stream>>>(
        (const float4*)x, sw, src, dst, out, n_edges);
}